// Round 5
// baseline (637.385 us; speedup 1.0000x reference)
//
#include <hip/hip_runtime.h>
#include <math.h>

#define BB   4
#define CC   256
#define HH   96
#define WW   96
#define OO   256
#define HW   9216        // HH*WW
#define KDIM 2304        // CC*9
#define OFFC 18
#define NKC  36          // K chunks of 64

// K ordering for the deform GEMM (split path): k' = tap*256 + c  (tap-major).
// V, Wb, and offset_meta's A/W staging all use k'; GEMM is ordering-agnostic.

typedef short bf16x8 __attribute__((ext_vector_type(8)));
typedef float f32x4  __attribute__((ext_vector_type(4)));
typedef unsigned int u32x4 __attribute__((ext_vector_type(4)));

// ---- ws layout (split path) ----
#define WS_V_SZ    (36864ull * 4608ull)               // V bf16 [p][k'], row 4608B, pre-swizzled
#define WS_WB_OFF  WS_V_SZ
#define WS_WB_SZ   (256ull * 4608ull)                 // W bf16 [o][k'], pre-swizzled
#define WS_META_OFF (WS_WB_OFF + WS_WB_SZ)
#define WS_META_SZ (4ull * 9ull * 9216ull * 16ull)    // uint4 per (b,tap,p)
#define WS_NEED    (WS_META_OFF + WS_META_SZ)         // ~176.4 MB

__device__ __forceinline__ unsigned short f2bfu(float f) {
    unsigned u = __float_as_uint(f);
    unsigned r = (u + 0x7fffu + ((u >> 16) & 1u)) >> 16;   // RNE
    return (unsigned short)r;
}
__device__ __forceinline__ unsigned pack2(float lo, float hi) {
    return (unsigned)f2bfu(lo) | ((unsigned)f2bfu(hi) << 16);
}
__device__ __forceinline__ void gload16(const void* g, void* l) {
    __builtin_amdgcn_global_load_lds((const __attribute__((address_space(1))) void*)g,
                                     (__attribute__((address_space(3))) void*)l, 16, 0, 0);
}

__device__ __forceinline__ uint4 make_meta(int pr, int t, float dy, float dx) {
    int oh = pr / WW, ow = pr - oh * WW;
    float py = (float)(oh - 1 + t / 3) + dy;
    float px = (float)(ow - 1 + (t % 3)) + dx;
    float y0f = floorf(py), x0f = floorf(px);
    int y0 = (int)y0f, x0 = (int)x0f;
    float ly = py - y0f, lx = px - x0f;
    float wy0 = (y0 >= 0 && y0 < HH) ? 1.f - ly : 0.f;
    float wy1 = (y0 + 1 >= 0 && y0 + 1 < HH) ? ly : 0.f;
    float u0 = (x0 >= 0 && x0 < WW) ? 1.f - lx : 0.f;
    float u1 = (x0 + 1 >= 0 && x0 + 1 < WW) ? lx : 0.f;
    int pb = min(max(x0, 0), WW - 2);
    float s0, s1;
    if (x0 < 0)           { s0 = u1; s1 = 0.f; }
    else if (x0 > WW - 2) { s0 = 0.f; s1 = u0; }
    else                  { s0 = u0; s1 = u1; }
    int cy0 = min(max(y0, 0), HH - 1);
    int cy1 = min(max(y0 + 1, 0), HH - 1);
    uint4 m;
    m.x = (unsigned)(cy0 * WW + pb);
    m.y = (unsigned)(cy1 * WW + pb);
    m.z = pack2(wy0 * s0, wy0 * s1);
    m.w = pack2(wy1 * s0, wy1 * s1);
    return m;
}

// ================= SPLIT PATH =================

// ---- Kernel A: offset conv via MFMA (64p x 32oc tile) + direct meta emission ----
// k' ordering: chunk kc -> tap = kc>>2, c-base = (kc&3)*64
__global__ __launch_bounds__(256)
void offset_meta_kernel(const float* __restrict__ x,
                        const float* __restrict__ w_off,
                        const float* __restrict__ b_off,
                        uint4* __restrict__ meta_ws)
{
    __shared__ __align__(16) char Asw[64 * 128];
    __shared__ __align__(16) char Wl[32 * 128];
    __shared__ float Dsh[64][21];

    const int tid = threadIdx.x;
    const int fin = ((blockIdx.x & 7) * 72) + (blockIdx.x >> 3);  // XCD-chunked (576 = 8*72)
    const int b   = fin / 144;
    const int pr0 = (fin % 144) * 64;
    const float* xb = x + (size_t)b * CC * HW;

    const int l15 = tid & 15;
    const int l4  = (tid >> 4) & 3;
    const int wav = tid >> 6;
    const int sp  = tid & 63;       // A staging: p row
    const int kq  = tid >> 6;       // A staging: c quarter (16 c)
    const int so  = tid >> 3;       // W staging: o row 0..31
    const int sq  = tid & 7;        // W staging: q group (8 c)

    const int prg = pr0 + sp;
    const int oh = prg / WW, ow = prg - (prg / WW) * WW;

    f32x4 acc[2];
    acc[0] = (f32x4){0.f, 0.f, 0.f, 0.f};
    acc[1] = (f32x4){0.f, 0.f, 0.f, 0.f};

    for (int kc = 0; kc < NKC; ++kc) {
        const int tap = kc >> 2;
        const int cb  = (kc & 3) * 64;
        // stage W (fp32 -> bf16, swizzled); rows 18..31 zero. w_off[so][c][tap], stride-9
        {
            uint4 pk;
            if (so < OFFC) {
                const float* wr = w_off + (size_t)so * KDIM + (cb + sq * 8) * 9 + tap;
                float wv[8];
                #pragma unroll
                for (int i = 0; i < 8; ++i) wv[i] = wr[i * 9];
                pk.x = pack2(wv[0], wv[1]); pk.y = pack2(wv[2], wv[3]);
                pk.z = pack2(wv[4], wv[5]); pk.w = pack2(wv[6], wv[7]);
            } else { pk.x = pk.y = pk.z = pk.w = 0u; }
            *(uint4*)(Wl + so * 128 + ((sq * 16) ^ ((so & 7) << 4))) = pk;
        }
        // stage A: static-tap gather, 16 c per thread (fixed tap -> bounds once)
        {
            int iy = oh + tap / 3 - 1;
            int ix = ow + tap % 3 - 1;
            bool ok = (iy >= 0) & (iy < HH) & (ix >= 0) & (ix < WW);
            const float* xp = xb + (size_t)(cb + kq * 16) * HW + iy * WW + ix;
            float v[16];
            #pragma unroll
            for (int e = 0; e < 16; ++e)
                v[e] = ok ? xp[(size_t)e * HW] : 0.f;
            char* arow = Asw + sp * 128;
            unsigned swz = (unsigned)((sp & 7) << 4);
            uint4 p0, p1;
            p0.x = pack2(v[0], v[1]);   p0.y = pack2(v[2], v[3]);
            p0.z = pack2(v[4], v[5]);   p0.w = pack2(v[6], v[7]);
            p1.x = pack2(v[8], v[9]);   p1.y = pack2(v[10], v[11]);
            p1.z = pack2(v[12], v[13]); p1.w = pack2(v[14], v[15]);
            *(uint4*)(arow + (((unsigned)(kq * 32 + 0)) ^ swz)) = p0;
            *(uint4*)(arow + (((unsigned)(kq * 32 + 16)) ^ swz)) = p1;
        }
        __syncthreads();
        // MFMA: wave handles p-frag wav*16, oc-frags 0..1
        {
            int p_loc = wav * 16 + l15;
            unsigned aswz = (unsigned)((p_loc & 7) << 4);
            #pragma unroll
            for (int ks = 0; ks < 2; ++ks) {
                bf16x8 a = *(const bf16x8*)(Asw + p_loc * 128 + ((ks * 64 + l4 * 16) ^ aswz));
                #pragma unroll
                for (int g = 0; g < 2; ++g) {
                    int o_loc = g * 16 + l15;
                    bf16x8 bw = *(const bf16x8*)(Wl + o_loc * 128 +
                                                 ((ks * 64 + l4 * 16) ^ ((o_loc & 7) << 4)));
                    acc[g] = __builtin_amdgcn_mfma_f32_16x16x32_bf16(a, bw, acc[g], 0, 0, 0);
                }
            }
        }
        __syncthreads();
    }

    // D -> LDS (rows p, cols oc<18), add bias
    #pragma unroll
    for (int g = 0; g < 2; ++g) {
        int o = g * 16 + l15;
        if (o < OFFC) {
            float bo = b_off[o];
            #pragma unroll
            for (int r = 0; r < 4; ++r)
                Dsh[wav * 16 + l4 * 4 + r][o] = acc[g][r] + bo;
        }
    }
    __syncthreads();
    // meta: 9 taps x 64 positions
    for (int s = tid; s < 9 * 64; s += 256) {
        int t = s >> 6, pl = s & 63;
        int pr = pr0 + pl;
        float dy = Dsh[pl][2 * t];
        float dx = Dsh[pl][2 * t + 1];
        meta_ws[((size_t)b * 9 + t) * HW + pr] = make_meta(pr, t, dy, dx);
    }
}

// ---- Kernel B: w_dc fp32 -> bf16 pre-swizzled, k' = tap*256 + c ----
__global__ __launch_bounds__(256)
void wconv_kernel(const float* __restrict__ w_dc, char* __restrict__ wb)
{
    int idx = blockIdx.x * 256 + (int)threadIdx.x;   // 73728 = 256 o * 288 (36 chunk * 8 q)
    int o   = idx / 288;
    int rem = idx - o * 288;
    int ch  = rem >> 3;          // chunk 0..35
    int q   = rem & 7;           // q group
    int tap = ch >> 2;
    int c0  = (ch & 3) * 64 + q * 8;
    const float* wr = w_dc + (size_t)o * KDIM + (size_t)c0 * 9 + tap;
    float wv[8];
    #pragma unroll
    for (int i = 0; i < 8; ++i) wv[i] = wr[i * 9];
    uint4 pk;
    pk.x = pack2(wv[0], wv[1]); pk.y = pack2(wv[2], wv[3]);
    pk.z = pack2(wv[4], wv[5]); pk.w = pack2(wv[6], wv[7]);
    *(uint4*)(wb + (size_t)o * 4608 + ch * 128 + ((q * 16) ^ ((o & 7) << 4))) = pk;
}

// ---- Kernel C: bilinear gather -> V[p][k'] bf16 (pre-swizzled rows) ----
// block = (b, pt, tap): 128 positions x 256 channels of one tap. Meta in regs.
__global__ __launch_bounds__(256, 8)
void gather_kernel2(const float* __restrict__ x,
                    const uint4* __restrict__ meta_ws,
                    char* __restrict__ Vg)
{
    __shared__ uint4 meta[128];

    int bid = blockIdx.x;                          // 2592 = 8 * 324
    int fin = (bid & 7) * 324 + (bid >> 3);        // XCD-chunked
    int tap = fin % 9;
    int ptg = fin / 9;                             // global p-tile 0..287
    int b   = ptg / 72;
    int tid = threadIdx.x;

    if (tid < 128)
        meta[tid] = meta_ws[((size_t)b * 9 + tap) * HW + (ptg % 72) * 128 + tid];
    __syncthreads();

    const int j = tid & 127, khalf = tid >> 7;
    uint4 m = meta[j];
    const float wa0 = __uint_as_float(m.z << 16);
    const float wa1 = __uint_as_float(m.z & 0xffff0000u);
    const float wb0 = __uint_as_float(m.w << 16);
    const float wb1 = __uint_as_float(m.w & 0xffff0000u);

    const float* xr = x + (size_t)(b * CC + khalf * 128) * HW;
    const float* pA = xr + m.x;
    const float* pB = xr + m.y;
    char* vrow = Vg + (size_t)(ptg * 128 + j) * 4608 + tap * 512 + khalf * 256;
    const unsigned swz = (unsigned)((j & 7) << 4);

    #pragma unroll
    for (int ch = 0; ch < 2; ++ch) {
        #pragma unroll
        for (int q = 0; q < 8; ++q) {
            float v[8];
            #pragma unroll
            for (int e = 0; e < 8; ++e) {
                float A0 = pA[0], A1 = pA[1];
                float B0 = pB[0], B1 = pB[1];
                v[e] = fmaf(wa0, A0, fmaf(wa1, A1, fmaf(wb0, B0, wb1 * B1)));
                pA += HW; pB += HW;
            }
            u32x4 pk;
            pk.x = pack2(v[0], v[1]); pk.y = pack2(v[2], v[3]);
            pk.z = pack2(v[4], v[5]); pk.w = pack2(v[6], v[7]);
            __builtin_nontemporal_store(pk, (u32x4*)(vrow + ch * 128 + ((q * 16) ^ swz)));
        }
    }
}

// ---- Kernel D: streaming GEMM, 2-phase double-buffered, global_load_lds ----
__global__ __launch_bounds__(256)
void gemm_kernel(const char* __restrict__ Vg, const char* __restrict__ Wb,
                 const float* __restrict__ b_dc, float* __restrict__ out)
{
    __shared__ __align__(16) char Ab[2][128 * 128];
    __shared__ __align__(16) char Bb[2][128 * 128];

    int bid = blockIdx.x;
    int swzb = (bid & 7) * 72 + (bid >> 3);   // both ot of a pt share an XCD
    int pt = swzb >> 1, ot = swzb & 1;
    int tid = threadIdx.x;
    int lane = tid & 63, wav = tid >> 6;
    const int l15 = tid & 15, l4 = (tid >> 4) & 3;
    const int wp = wav >> 1, wo = wav & 1;

    const char* Ag = Vg + (size_t)(pt * 128) * 4608;
    const char* Bg = Wb + (size_t)(ot * 128) * 4608;
    const int rsub = lane >> 3;
    const int csub = (lane & 7) * 16;

    f32x4 acc[4][4];
    #pragma unroll
    for (int f = 0; f < 4; ++f)
        #pragma unroll
        for (int g = 0; g < 4; ++g)
            acc[f][g] = (f32x4){0.f, 0.f, 0.f, 0.f};

#define STAGE(bufi, t) {                                                        \
        const char* ag = Ag + (size_t)(t) * 128;                                \
        const char* bg = Bg + (size_t)(t) * 128;                                \
        _Pragma("unroll")                                                       \
        for (int i = 0; i < 4; ++i) {                                           \
            int r0 = wav * 32 + i * 8;                                          \
            gload16(ag + (size_t)(r0 + rsub) * 4608 + csub, &Ab[bufi][r0 * 128]);\
            gload16(bg + (size_t)(r0 + rsub) * 4608 + csub, &Bb[bufi][r0 * 128]);\
        } }

    STAGE(0, 0);
    __syncthreads();

    int cur = 0;
    for (int t = 0; t < NKC; ++t) {
        if (t + 1 < NKC) STAGE(cur ^ 1, t + 1);
        #pragma unroll
        for (int ks = 0; ks < 2; ++ks) {
            bf16x8 a[4], bw[4];
            #pragma unroll
            for (int f = 0; f < 4; ++f) {
                int p_loc = wp * 64 + f * 16 + l15;
                a[f] = *(const bf16x8*)(Ab[cur] + p_loc * 128 +
                                        ((ks * 64 + l4 * 16) ^ ((p_loc & 7) << 4)));
            }
            #pragma unroll
            for (int g = 0; g < 4; ++g) {
                int o_loc = wo * 64 + g * 16 + l15;
                bw[g] = *(const bf16x8*)(Bb[cur] + o_loc * 128 +
                                         ((ks * 64 + l4 * 16) ^ ((o_loc & 7) << 4)));
            }
            #pragma unroll
            for (int f = 0; f < 4; ++f)
                #pragma unroll
                for (int g = 0; g < 4; ++g)
                    acc[f][g] = __builtin_amdgcn_mfma_f32_16x16x32_bf16(a[f], bw[g], acc[f][g], 0, 0, 0);
        }
        __syncthreads();
        cur ^= 1;
    }

    int b = pt / 72;
    int posr = (pt - b * 72) * 128;
    #pragma unroll
    for (int g = 0; g < 4; ++g) {
        int og = ot * 128 + wo * 64 + g * 16 + l15;
        float bias = b_dc[og];
        float* op = out + ((size_t)b * OO + og) * HW + posr + wp * 64 + l4 * 4;
        #pragma unroll
        for (int f = 0; f < 4; ++f) {
            f32x4 r = acc[f][g];
            float4 st;
            st.x = r[0] + bias; st.y = r[1] + bias;
            st.z = r[2] + bias; st.w = r[3] + bias;
            *(float4*)(op + f * 16) = st;
        }
    }
}

// ================= FALLBACK PATH (round-2, verified; self-consistent k ordering) =================

__global__ __launch_bounds__(256)
void offset_conv6_kernel(const float* __restrict__ x,
                         const float* __restrict__ w_off,
                         const float* __restrict__ b_off,
                         float* __restrict__ off)
{
    int bid   = blockIdx.x;
    int g     = bid % 3;
    int chunk = (bid / 3) % 36;
    int b     = bid / 108;
    int ocb   = g * 6;
    int pr    = chunk * 256 + (int)threadIdx.x;
    int oh    = pr / WW, ow = pr % WW;
    const float* xb = x + (size_t)b * CC * HW;

    float acc[6];
    #pragma unroll
    for (int i = 0; i < 6; ++i) acc[i] = b_off[ocb + i];

    bool interior = (oh >= 1) & (oh < HH - 1) & (ow >= 1) & (ow < WW - 1);
    if (interior) {
        const float* xp = xb + (oh - 1) * WW + (ow - 1);
        float xv[9];
        #pragma unroll
        for (int t = 0; t < 9; ++t) xv[t] = xp[(t / 3) * WW + (t % 3)];
        for (int c = 0; c < CC; ++c) {
            float xn[9];
            if (c + 1 < CC) {
                const float* xq = xp + (size_t)(c + 1) * HW;
                #pragma unroll
                for (int t = 0; t < 9; ++t) xn[t] = xq[(t / 3) * WW + (t % 3)];
            }
            #pragma unroll
            for (int i = 0; i < 6; ++i) {
                const float* wr = w_off + ((size_t)(ocb + i) * CC + c) * 9;
                #pragma unroll
                for (int t = 0; t < 9; ++t)
                    acc[i] = fmaf(xv[t], wr[t], acc[i]);
            }
            #pragma unroll
            for (int t = 0; t < 9; ++t) xv[t] = xn[t];
        }
    } else {
        for (int c = 0; c < CC; ++c) {
            const float* xc = xb + (size_t)c * HW;
            float xv[9];
            #pragma unroll
            for (int t = 0; t < 9; ++t) {
                int yy = oh + t / 3 - 1, xx = ow + t % 3 - 1;
                xv[t] = (yy >= 0 && yy < HH && xx >= 0 && xx < WW) ? xc[yy * WW + xx] : 0.f;
            }
            #pragma unroll
            for (int i = 0; i < 6; ++i) {
                const float* wr = w_off + ((size_t)(ocb + i) * CC + c) * 9;
                #pragma unroll
                for (int t = 0; t < 9; ++t)
                    acc[i] = fmaf(xv[t], wr[t], acc[i]);
            }
        }
    }
    #pragma unroll
    for (int i = 0; i < 6; ++i)
        off[((size_t)b * OFFC + ocb + i) * HW + pr] = acc[i];
}

__global__ __launch_bounds__(256)
void deform_mfma_kernel(const float* __restrict__ x,
                        const float* __restrict__ off,
                        const float* __restrict__ w_dc,
                        const float* __restrict__ b_dc,
                        float* __restrict__ out)
{
    __shared__ __align__(16) char VlB[128 * 128];
    __shared__ __align__(16) char WlB[128 * 128];
    __shared__ uint4 meta[9][128];

    const int tid  = threadIdx.x;
    const int ot   = blockIdx.x / 288;
    const int pt   = blockIdx.x % 288;
    const int pos0 = pt * 128;
    const int b    = pos0 / HW;
    const int posr = pos0 - b * HW;

    const float* offp = off + (size_t)b * OFFC * HW;
    for (int s = tid; s < 9 * 128; s += 256) {
        int tt = s >> 7, j = s & 127;
        int pr = posr + j;
        float dy = offp[(2 * tt) * HW + pr];
        float dx = offp[(2 * tt + 1) * HW + pr];
        meta[tt][j] = make_meta(pr, tt, dy, dx);
    }
    __syncthreads();

    const int l15 = tid & 15;
    const int l4  = (tid >> 4) & 3;
    const int wav = tid >> 6;
    const int wp  = wav >> 1, wwo = wav & 1;
    const int j     = tid & 127;
    const int khalf = tid >> 7;
    const int wo_o  = tid >> 4;
    const int wk    = (tid & 15) * 4;

    const float* wbase = w_dc + (size_t)(ot * 128) * KDIM;

    f32x4 acc[4][4];
    #pragma unroll
    for (int f = 0; f < 4; ++f)
        #pragma unroll
        for (int g = 0; g < 4; ++g)
            acc[f][g] = (f32x4){0.f, 0.f, 0.f, 0.f};

    for (int k0 = 0; k0 < KDIM; k0 += 64) {
        #pragma unroll
        for (int r = 0; r < 8; ++r) {
            int o = r * 16 + wo_o;
            const float4 wv = *(const float4*)(wbase + (size_t)o * KDIM + k0 + wk);
            uint2 u;
            u.x = pack2(wv.x, wv.y);
            u.y = pack2(wv.z, wv.w);
            *(uint2*)(WlB + o * 128 + ((wk * 2) ^ ((o & 7) << 4))) = u;
        }
        {
            unsigned kb = (unsigned)(k0 + khalf * 32);
            unsigned c  = kb / 9u;
            unsigned tt = kb - c * 9u;
            const float* xc = x + (size_t)((unsigned)b * CC + c) * HW;
            char* vrow = VlB + j * 128;
            const unsigned swz = (unsigned)((j & 7) << 4);
            #pragma unroll
            for (int g = 0; g < 4; ++g) {
                float v[8];
                #pragma unroll
                for (int e = 0; e < 8; ++e) {
                    uint4 m = meta[tt][j];
                    float A0 = xc[m.x], A1 = xc[m.x + 1];
                    float B0 = xc[m.y], B1 = xc[m.y + 1];
                    float a0 = __uint_as_float(m.z << 16);
                    float a1 = __uint_as_float(m.z & 0xffff0000u);
                    float b0 = __uint_as_float(m.w << 16);
                    float b1 = __uint_as_float(m.w & 0xffff0000u);
                    v[e] = fmaf(a0, A0, fmaf(a1, A1, fmaf(b0, B0, b1 * B1)));
                    ++tt;
                    if (tt == 9u) { tt = 0u; xc += HW; }
                }
                uint4 pk;
                pk.x = pack2(v[0], v[1]); pk.y = pack2(v[2], v[3]);
                pk.z = pack2(v[4], v[5]); pk.w = pack2(v[6], v[7]);
                *(uint4*)(vrow + (((unsigned)(khalf * 64 + g * 16)) ^ swz)) = pk;
            }
        }
        __syncthreads();

        #pragma unroll
        for (int ks = 0; ks < 2; ++ks) {
            bf16x8 a[4], bw[4];
            #pragma unroll
            for (int f = 0; f < 4; ++f) {
                int p_loc = wp * 64 + f * 16 + l15;
                a[f] = *(const bf16x8*)(VlB + p_loc * 128 +
                                        ((ks * 64 + l4 * 16) ^ ((p_loc & 7) << 4)));
            }
            #pragma unroll
            for (int g = 0; g < 4; ++g) {
                int o_loc = wwo * 64 + g * 16 + l15;
                bw[g] = *(const bf16x8*)(WlB + o_loc * 128 +
                                         ((ks * 64 + l4 * 16) ^ ((o_loc & 7) << 4)));
            }
            #pragma unroll
            for (int f = 0; f < 4; ++f)
                #pragma unroll
                for (int g = 0; g < 4; ++g)
                    acc[f][g] = __builtin_amdgcn_mfma_f32_16x16x32_bf16(a[f], bw[g], acc[f][g], 0, 0, 0);
        }
        __syncthreads();
    }

    #pragma unroll
    for (int g = 0; g < 4; ++g) {
        int og = ot * 128 + wwo * 64 + g * 16 + l15;
        float bias = b_dc[og];
        float* op = out + ((size_t)b * OO + og) * HW + posr + wp * 64 + l4 * 4;
        #pragma unroll
        for (int f = 0; f < 4; ++f) {
            f32x4 r = acc[f][g];
            float4 st;
            st.x = r[0] + bias; st.y = r[1] + bias;
            st.z = r[2] + bias; st.w = r[3] + bias;
            *(float4*)(op + f * 16) = st;
        }
    }
}

extern "C" void kernel_launch(void* const* d_in, const int* in_sizes, int n_in,
                              void* d_out, int out_size, void* d_ws, size_t ws_size,
                              hipStream_t stream)
{
    const float* x     = (const float*)d_in[0];
    const float* w_off = (const float*)d_in[1];
    const float* b_off = (const float*)d_in[2];
    const float* w_dc  = (const float*)d_in[3];
    const float* b_dc  = (const float*)d_in[4];
    float* out = (float*)d_out;

    if (ws_size >= WS_NEED) {
        char*  ws   = (char*)d_ws;
        char*  Vg   = ws;
        char*  Wb   = ws + WS_WB_OFF;
        uint4* meta = (uint4*)(ws + WS_META_OFF);
        offset_meta_kernel<<<BB * 144, 256, 0, stream>>>(x, w_off, b_off, meta);
        wconv_kernel<<<288, 256, 0, stream>>>(w_dc, Wb);
        gather_kernel2<<<288 * 9, 256, 0, stream>>>(x, meta, Vg);
        gemm_kernel<<<576, 256, 0, stream>>>(Vg, Wb, b_dc, out);
    } else {
        float* off = (float*)d_ws;
        offset_conv6_kernel<<<BB * 36 * 3, 256, 0, stream>>>(x, w_off, b_off, off);
        deform_mfma_kernel<<<(OO / 128) * (BB * HW / 128), 256, 0, stream>>>(x, off, w_dc, b_dc, out);
    }
}

// Round 6
// 628.726 us; speedup vs baseline: 1.0138x; 1.0138x over previous
//
#include <hip/hip_runtime.h>
#include <math.h>

#define BB   4
#define CC   256
#define HH   96
#define WW   96
#define OO   256
#define HW   9216        // HH*WW
#define KDIM 2304        // CC*9
#define OFFC 18
#define NKC  36          // K chunks of 64

// K ordering for the deform GEMM (split path): k' = tap*256 + c  (tap-major).
// V, Wb, and offset_meta's A/W staging all use k'; GEMM is ordering-agnostic.

typedef short bf16x8 __attribute__((ext_vector_type(8)));
typedef float f32x4  __attribute__((ext_vector_type(4)));
typedef unsigned int u32x4 __attribute__((ext_vector_type(4)));

// ---- ws layout (split path) ----
#define WS_V_SZ    (36864ull * 4608ull)               // V bf16 [p][k'], row 4608B, pre-swizzled
#define WS_WB_OFF  WS_V_SZ
#define WS_WB_SZ   (256ull * 4608ull)                 // W bf16 [o][k'], pre-swizzled
#define WS_META_OFF (WS_WB_OFF + WS_WB_SZ)
#define WS_META_SZ (4ull * 9ull * 9216ull * 16ull)    // uint4 per (b,tap,p)
#define WS_NEED    (WS_META_OFF + WS_META_SZ)         // ~176.4 MB

__device__ __forceinline__ unsigned short f2bfu(float f) {
    unsigned u = __float_as_uint(f);
    unsigned r = (u + 0x7fffu + ((u >> 16) & 1u)) >> 16;   // RNE
    return (unsigned short)r;
}
__device__ __forceinline__ unsigned pack2(float lo, float hi) {
    return (unsigned)f2bfu(lo) | ((unsigned)f2bfu(hi) << 16);
}
__device__ __forceinline__ void gload16(const void* g, void* l) {
    __builtin_amdgcn_global_load_lds((const __attribute__((address_space(1))) void*)g,
                                     (__attribute__((address_space(3))) void*)l, 16, 0, 0);
}

__device__ __forceinline__ uint4 make_meta(int pr, int t, float dy, float dx) {
    int oh = pr / WW, ow = pr - oh * WW;
    float py = (float)(oh - 1 + t / 3) + dy;
    float px = (float)(ow - 1 + (t % 3)) + dx;
    float y0f = floorf(py), x0f = floorf(px);
    int y0 = (int)y0f, x0 = (int)x0f;
    float ly = py - y0f, lx = px - x0f;
    float wy0 = (y0 >= 0 && y0 < HH) ? 1.f - ly : 0.f;
    float wy1 = (y0 + 1 >= 0 && y0 + 1 < HH) ? ly : 0.f;
    float u0 = (x0 >= 0 && x0 < WW) ? 1.f - lx : 0.f;
    float u1 = (x0 + 1 >= 0 && x0 + 1 < WW) ? lx : 0.f;
    int pb = min(max(x0, 0), WW - 2);
    float s0, s1;
    if (x0 < 0)           { s0 = u1; s1 = 0.f; }
    else if (x0 > WW - 2) { s0 = 0.f; s1 = u0; }
    else                  { s0 = u0; s1 = u1; }
    int cy0 = min(max(y0, 0), HH - 1);
    int cy1 = min(max(y0 + 1, 0), HH - 1);
    uint4 m;
    m.x = (unsigned)(cy0 * WW + pb);
    m.y = (unsigned)(cy1 * WW + pb);
    m.z = pack2(wy0 * s0, wy0 * s1);
    m.w = pack2(wy1 * s0, wy1 * s1);
    return m;
}

// ================= SPLIT PATH =================

// ---- Kernel A: offset conv via MFMA (64p x 32oc tile) + direct meta emission ----
// k' ordering: chunk kc -> tap = kc>>2, c-base = (kc&3)*64
__global__ __launch_bounds__(256)
void offset_meta_kernel(const float* __restrict__ x,
                        const float* __restrict__ w_off,
                        const float* __restrict__ b_off,
                        uint4* __restrict__ meta_ws)
{
    __shared__ __align__(16) char Asw[64 * 128];
    __shared__ __align__(16) char Wl[32 * 128];
    __shared__ float Dsh[64][21];

    const int tid = threadIdx.x;
    const int fin = ((blockIdx.x & 7) * 72) + (blockIdx.x >> 3);  // XCD-chunked (576 = 8*72)
    const int b   = fin / 144;
    const int pr0 = (fin % 144) * 64;
    const float* xb = x + (size_t)b * CC * HW;

    const int l15 = tid & 15;
    const int l4  = (tid >> 4) & 3;
    const int wav = tid >> 6;
    const int sp  = tid & 63;       // A staging: p row
    const int kq  = tid >> 6;       // A staging: c quarter (16 c)
    const int so  = tid >> 3;       // W staging: o row 0..31
    const int sq  = tid & 7;        // W staging: q group (8 c)

    const int prg = pr0 + sp;
    const int oh = prg / WW, ow = prg - (prg / WW) * WW;

    f32x4 acc[2];
    acc[0] = (f32x4){0.f, 0.f, 0.f, 0.f};
    acc[1] = (f32x4){0.f, 0.f, 0.f, 0.f};

    for (int kc = 0; kc < NKC; ++kc) {
        const int tap = kc >> 2;
        const int cb  = (kc & 3) * 64;
        // stage W (fp32 -> bf16, swizzled); rows 18..31 zero. w_off[so][c][tap], stride-9
        {
            uint4 pk;
            if (so < OFFC) {
                const float* wr = w_off + (size_t)so * KDIM + (cb + sq * 8) * 9 + tap;
                float wv[8];
                #pragma unroll
                for (int i = 0; i < 8; ++i) wv[i] = wr[i * 9];
                pk.x = pack2(wv[0], wv[1]); pk.y = pack2(wv[2], wv[3]);
                pk.z = pack2(wv[4], wv[5]); pk.w = pack2(wv[6], wv[7]);
            } else { pk.x = pk.y = pk.z = pk.w = 0u; }
            *(uint4*)(Wl + so * 128 + ((sq * 16) ^ ((so & 7) << 4))) = pk;
        }
        // stage A: static-tap gather, 16 c per thread (fixed tap -> bounds once)
        {
            int iy = oh + tap / 3 - 1;
            int ix = ow + tap % 3 - 1;
            bool ok = (iy >= 0) & (iy < HH) & (ix >= 0) & (ix < WW);
            const float* xp = xb + (size_t)(cb + kq * 16) * HW + iy * WW + ix;
            float v[16];
            #pragma unroll
            for (int e = 0; e < 16; ++e)
                v[e] = ok ? xp[(size_t)e * HW] : 0.f;
            char* arow = Asw + sp * 128;
            unsigned swz = (unsigned)((sp & 7) << 4);
            uint4 p0, p1;
            p0.x = pack2(v[0], v[1]);   p0.y = pack2(v[2], v[3]);
            p0.z = pack2(v[4], v[5]);   p0.w = pack2(v[6], v[7]);
            p1.x = pack2(v[8], v[9]);   p1.y = pack2(v[10], v[11]);
            p1.z = pack2(v[12], v[13]); p1.w = pack2(v[14], v[15]);
            *(uint4*)(arow + (((unsigned)(kq * 32 + 0)) ^ swz)) = p0;
            *(uint4*)(arow + (((unsigned)(kq * 32 + 16)) ^ swz)) = p1;
        }
        __syncthreads();
        // MFMA: wave handles p-frag wav*16, oc-frags 0..1
        {
            int p_loc = wav * 16 + l15;
            unsigned aswz = (unsigned)((p_loc & 7) << 4);
            #pragma unroll
            for (int ks = 0; ks < 2; ++ks) {
                bf16x8 a = *(const bf16x8*)(Asw + p_loc * 128 + ((ks * 64 + l4 * 16) ^ aswz));
                #pragma unroll
                for (int g = 0; g < 2; ++g) {
                    int o_loc = g * 16 + l15;
                    bf16x8 bw = *(const bf16x8*)(Wl + o_loc * 128 +
                                                 ((ks * 64 + l4 * 16) ^ ((o_loc & 7) << 4)));
                    acc[g] = __builtin_amdgcn_mfma_f32_16x16x32_bf16(a, bw, acc[g], 0, 0, 0);
                }
            }
        }
        __syncthreads();
    }

    // D -> LDS (rows p, cols oc<18), add bias
    #pragma unroll
    for (int g = 0; g < 2; ++g) {
        int o = g * 16 + l15;
        if (o < OFFC) {
            float bo = b_off[o];
            #pragma unroll
            for (int r = 0; r < 4; ++r)
                Dsh[wav * 16 + l4 * 4 + r][o] = acc[g][r] + bo;
        }
    }
    __syncthreads();
    // meta: 9 taps x 64 positions
    for (int s = tid; s < 9 * 64; s += 256) {
        int t = s >> 6, pl = s & 63;
        int pr = pr0 + pl;
        float dy = Dsh[pl][2 * t];
        float dx = Dsh[pl][2 * t + 1];
        meta_ws[((size_t)b * 9 + t) * HW + pr] = make_meta(pr, t, dy, dx);
    }
}

// ---- Kernel B: w_dc fp32 -> bf16 pre-swizzled, k' = tap*256 + c ----
__global__ __launch_bounds__(256)
void wconv_kernel(const float* __restrict__ w_dc, char* __restrict__ wb)
{
    int idx = blockIdx.x * 256 + (int)threadIdx.x;   // 73728 = 256 o * 288 (36 chunk * 8 q)
    int o   = idx / 288;
    int rem = idx - o * 288;
    int ch  = rem >> 3;          // chunk 0..35
    int q   = rem & 7;           // q group
    int tap = ch >> 2;
    int c0  = (ch & 3) * 64 + q * 8;
    const float* wr = w_dc + (size_t)o * KDIM + (size_t)c0 * 9 + tap;
    float wv[8];
    #pragma unroll
    for (int i = 0; i < 8; ++i) wv[i] = wr[i * 9];
    uint4 pk;
    pk.x = pack2(wv[0], wv[1]); pk.y = pack2(wv[2], wv[3]);
    pk.z = pack2(wv[4], wv[5]); pk.w = pack2(wv[6], wv[7]);
    *(uint4*)(wb + (size_t)o * 4608 + ch * 128 + ((q * 16) ^ ((o & 7) << 4))) = pk;
}

// ---- Kernel C: bilinear gather -> V[p][k'] bf16 (pre-swizzled rows) ----
// block = (b, pt, tap). Thread = (row r, 16B chunk ch): lanes 0..31 cover one
// row's full 512B tap region -> wave stores are full-line coalesced (no RMW).
__global__ __launch_bounds__(256, 8)
void gather_kernel3(const float* __restrict__ x,
                    const uint4* __restrict__ meta_ws,
                    char* __restrict__ Vg)
{
    __shared__ uint4 meta[128];

    int bid = blockIdx.x;                          // 2592 = 8 * 324
    int fin = (bid & 7) * 324 + (bid >> 3);        // XCD-chunked
    int tap = fin % 9;
    int ptg = fin / 9;                             // global p-tile 0..287
    int b   = ptg / 72;
    int tid = threadIdx.x;

    if (tid < 128)
        meta[tid] = meta_ws[((size_t)b * 9 + tap) * HW + (ptg % 72) * 128 + tid];
    __syncthreads();

    const int ch = tid & 31;      // 16B chunk within the 512B tap region (c = ch*8..ch*8+7)
    const int r  = tid >> 5;      // row sub-index 0..7
    const float* xc = x + ((size_t)b * CC + ch * 8) * HW;
    char* base = Vg + (size_t)(ptg * 128) * 4608 + tap * 512;

    #pragma unroll 4
    for (int it = 0; it < 16; ++it) {
        int row = it * 8 + r;
        uint4 m = meta[row];
        float wa0 = __uint_as_float(m.z << 16);
        float wa1 = __uint_as_float(m.z & 0xffff0000u);
        float wb0 = __uint_as_float(m.w << 16);
        float wb1 = __uint_as_float(m.w & 0xffff0000u);
        const float* pA = xc + m.x;
        const float* pB = xc + m.y;
        float v[8];
        #pragma unroll
        for (int e = 0; e < 8; ++e) {
            float A0 = pA[0], A1 = pA[1];
            float B0 = pB[0], B1 = pB[1];
            v[e] = fmaf(wa0, A0, fmaf(wa1, A1, fmaf(wb0, B0, wb1 * B1)));
            pA += HW; pB += HW;
        }
        u32x4 pk;
        pk.x = pack2(v[0], v[1]); pk.y = pack2(v[2], v[3]);
        pk.z = pack2(v[4], v[5]); pk.w = pack2(v[6], v[7]);
        __builtin_nontemporal_store(pk,
            (u32x4*)(base + (size_t)row * 4608 + ((ch * 16) ^ ((row & 7) << 4))));
    }
}

// ---- Kernel D: streaming GEMM, 2-phase double-buffered, global_load_lds ----
__global__ __launch_bounds__(256)
void gemm_kernel(const char* __restrict__ Vg, const char* __restrict__ Wb,
                 const float* __restrict__ b_dc, float* __restrict__ out)
{
    __shared__ __align__(16) char Ab[2][128 * 128];
    __shared__ __align__(16) char Bb[2][128 * 128];

    int bid = blockIdx.x;
    int swzb = (bid & 7) * 72 + (bid >> 3);   // both ot of a pt share an XCD
    int pt = swzb >> 1, ot = swzb & 1;
    int tid = threadIdx.x;
    int lane = tid & 63, wav = tid >> 6;
    const int l15 = tid & 15, l4 = (tid >> 4) & 3;
    const int wp = wav >> 1, wo = wav & 1;

    const char* Ag = Vg + (size_t)(pt * 128) * 4608;
    const char* Bg = Wb + (size_t)(ot * 128) * 4608;
    const int rsub = lane >> 3;
    const int csub = (lane & 7) * 16;

    f32x4 acc[4][4];
    #pragma unroll
    for (int f = 0; f < 4; ++f)
        #pragma unroll
        for (int g = 0; g < 4; ++g)
            acc[f][g] = (f32x4){0.f, 0.f, 0.f, 0.f};

#define STAGE(bufi, t) {                                                        \
        const char* ag = Ag + (size_t)(t) * 128;                                \
        const char* bg = Bg + (size_t)(t) * 128;                                \
        _Pragma("unroll")                                                       \
        for (int i = 0; i < 4; ++i) {                                           \
            int r0 = wav * 32 + i * 8;                                          \
            gload16(ag + (size_t)(r0 + rsub) * 4608 + csub, &Ab[bufi][r0 * 128]);\
            gload16(bg + (size_t)(r0 + rsub) * 4608 + csub, &Bb[bufi][r0 * 128]);\
        } }

    STAGE(0, 0);
    __syncthreads();

    int cur = 0;
    for (int t = 0; t < NKC; ++t) {
        if (t + 1 < NKC) STAGE(cur ^ 1, t + 1);
        #pragma unroll
        for (int ks = 0; ks < 2; ++ks) {
            bf16x8 a[4], bw[4];
            #pragma unroll
            for (int f = 0; f < 4; ++f) {
                int p_loc = wp * 64 + f * 16 + l15;
                a[f] = *(const bf16x8*)(Ab[cur] + p_loc * 128 +
                                        ((ks * 64 + l4 * 16) ^ ((p_loc & 7) << 4)));
            }
            #pragma unroll
            for (int g = 0; g < 4; ++g) {
                int o_loc = wo * 64 + g * 16 + l15;
                bw[g] = *(const bf16x8*)(Bb[cur] + o_loc * 128 +
                                         ((ks * 64 + l4 * 16) ^ ((o_loc & 7) << 4)));
            }
            #pragma unroll
            for (int f = 0; f < 4; ++f)
                #pragma unroll
                for (int g = 0; g < 4; ++g)
                    acc[f][g] = __builtin_amdgcn_mfma_f32_16x16x32_bf16(a[f], bw[g], acc[f][g], 0, 0, 0);
        }
        __syncthreads();
        cur ^= 1;
    }

    int b = pt / 72;
    int posr = (pt - b * 72) * 128;
    #pragma unroll
    for (int g = 0; g < 4; ++g) {
        int og = ot * 128 + wo * 64 + g * 16 + l15;
        float bias = b_dc[og];
        float* op = out + ((size_t)b * OO + og) * HW + posr + wp * 64 + l4 * 4;
        #pragma unroll
        for (int f = 0; f < 4; ++f) {
            f32x4 r = acc[f][g];
            float4 st;
            st.x = r[0] + bias; st.y = r[1] + bias;
            st.z = r[2] + bias; st.w = r[3] + bias;
            *(float4*)(op + f * 16) = st;
        }
    }
}

// ================= FALLBACK PATH (round-2, verified; self-consistent k ordering) =================

__global__ __launch_bounds__(256)
void offset_conv6_kernel(const float* __restrict__ x,
                         const float* __restrict__ w_off,
                         const float* __restrict__ b_off,
                         float* __restrict__ off)
{
    int bid   = blockIdx.x;
    int g     = bid % 3;
    int chunk = (bid / 3) % 36;
    int b     = bid / 108;
    int ocb   = g * 6;
    int pr    = chunk * 256 + (int)threadIdx.x;
    int oh    = pr / WW, ow = pr % WW;
    const float* xb = x + (size_t)b * CC * HW;

    float acc[6];
    #pragma unroll
    for (int i = 0; i < 6; ++i) acc[i] = b_off[ocb + i];

    bool interior = (oh >= 1) & (oh < HH - 1) & (ow >= 1) & (ow < WW - 1);
    if (interior) {
        const float* xp = xb + (oh - 1) * WW + (ow - 1);
        float xv[9];
        #pragma unroll
        for (int t = 0; t < 9; ++t) xv[t] = xp[(t / 3) * WW + (t % 3)];
        for (int c = 0; c < CC; ++c) {
            float xn[9];
            if (c + 1 < CC) {
                const float* xq = xp + (size_t)(c + 1) * HW;
                #pragma unroll
                for (int t = 0; t < 9; ++t) xn[t] = xq[(t / 3) * WW + (t % 3)];
            }
            #pragma unroll
            for (int i = 0; i < 6; ++i) {
                const float* wr = w_off + ((size_t)(ocb + i) * CC + c) * 9;
                #pragma unroll
                for (int t = 0; t < 9; ++t)
                    acc[i] = fmaf(xv[t], wr[t], acc[i]);
            }
            #pragma unroll
            for (int t = 0; t < 9; ++t) xv[t] = xn[t];
        }
    } else {
        for (int c = 0; c < CC; ++c) {
            const float* xc = xb + (size_t)c * HW;
            float xv[9];
            #pragma unroll
            for (int t = 0; t < 9; ++t) {
                int yy = oh + t / 3 - 1, xx = ow + t % 3 - 1;
                xv[t] = (yy >= 0 && yy < HH && xx >= 0 && xx < WW) ? xc[yy * WW + xx] : 0.f;
            }
            #pragma unroll
            for (int i = 0; i < 6; ++i) {
                const float* wr = w_off + ((size_t)(ocb + i) * CC + c) * 9;
                #pragma unroll
                for (int t = 0; t < 9; ++t)
                    acc[i] = fmaf(xv[t], wr[t], acc[i]);
            }
        }
    }
    #pragma unroll
    for (int i = 0; i < 6; ++i)
        off[((size_t)b * OFFC + ocb + i) * HW + pr] = acc[i];
}

__global__ __launch_bounds__(256)
void deform_mfma_kernel(const float* __restrict__ x,
                        const float* __restrict__ off,
                        const float* __restrict__ w_dc,
                        const float* __restrict__ b_dc,
                        float* __restrict__ out)
{
    __shared__ __align__(16) char VlB[128 * 128];
    __shared__ __align__(16) char WlB[128 * 128];
    __shared__ uint4 meta[9][128];

    const int tid  = threadIdx.x;
    const int ot   = blockIdx.x / 288;
    const int pt   = blockIdx.x % 288;
    const int pos0 = pt * 128;
    const int b    = pos0 / HW;
    const int posr = pos0 - b * HW;

    const float* offp = off + (size_t)b * OFFC * HW;
    for (int s = tid; s < 9 * 128; s += 256) {
        int tt = s >> 7, j = s & 127;
        int pr = posr + j;
        float dy = offp[(2 * tt) * HW + pr];
        float dx = offp[(2 * tt + 1) * HW + pr];
        meta[tt][j] = make_meta(pr, tt, dy, dx);
    }
    __syncthreads();

    const int l15 = tid & 15;
    const int l4  = (tid >> 4) & 3;
    const int wav = tid >> 6;
    const int wp  = wav >> 1, wwo = wav & 1;
    const int j     = tid & 127;
    const int khalf = tid >> 7;
    const int wo_o  = tid >> 4;
    const int wk    = (tid & 15) * 4;

    const float* wbase = w_dc + (size_t)(ot * 128) * KDIM;

    f32x4 acc[4][4];
    #pragma unroll
    for (int f = 0; f < 4; ++f)
        #pragma unroll
        for (int g = 0; g < 4; ++g)
            acc[f][g] = (f32x4){0.f, 0.f, 0.f, 0.f};

    for (int k0 = 0; k0 < KDIM; k0 += 64) {
        #pragma unroll
        for (int r = 0; r < 8; ++r) {
            int o = r * 16 + wo_o;
            const float4 wv = *(const float4*)(wbase + (size_t)o * KDIM + k0 + wk);
            uint2 u;
            u.x = pack2(wv.x, wv.y);
            u.y = pack2(wv.z, wv.w);
            *(uint2*)(WlB + o * 128 + ((wk * 2) ^ ((o & 7) << 4))) = u;
        }
        {
            unsigned kb = (unsigned)(k0 + khalf * 32);
            unsigned c  = kb / 9u;
            unsigned tt = kb - c * 9u;
            const float* xc = x + (size_t)((unsigned)b * CC + c) * HW;
            char* vrow = VlB + j * 128;
            const unsigned swz = (unsigned)((j & 7) << 4);
            #pragma unroll
            for (int g = 0; g < 4; ++g) {
                float v[8];
                #pragma unroll
                for (int e = 0; e < 8; ++e) {
                    uint4 m = meta[tt][j];
                    float A0 = xc[m.x], A1 = xc[m.x + 1];
                    float B0 = xc[m.y], B1 = xc[m.y + 1];
                    float a0 = __uint_as_float(m.z << 16);
                    float a1 = __uint_as_float(m.z & 0xffff0000u);
                    float b0 = __uint_as_float(m.w << 16);
                    float b1 = __uint_as_float(m.w & 0xffff0000u);
                    v[e] = fmaf(a0, A0, fmaf(a1, A1, fmaf(b0, B0, b1 * B1)));
                    ++tt;
                    if (tt == 9u) { tt = 0u; xc += HW; }
                }
                uint4 pk;
                pk.x = pack2(v[0], v[1]); pk.y = pack2(v[2], v[3]);
                pk.z = pack2(v[4], v[5]); pk.w = pack2(v[6], v[7]);
                *(uint4*)(vrow + (((unsigned)(khalf * 64 + g * 16)) ^ swz)) = pk;
            }
        }
        __syncthreads();

        #pragma unroll
        for (int ks = 0; ks < 2; ++ks) {
            bf16x8 a[4], bw[4];
            #pragma unroll
            for (int f = 0; f < 4; ++f) {
                int p_loc = wp * 64 + f * 16 + l15;
                a[f] = *(const bf16x8*)(VlB + p_loc * 128 +
                                        ((ks * 64 + l4 * 16) ^ ((p_loc & 7) << 4)));
            }
            #pragma unroll
            for (int g = 0; g < 4; ++g) {
                int o_loc = wwo * 64 + g * 16 + l15;
                bw[g] = *(const bf16x8*)(WlB + o_loc * 128 +
                                         ((ks * 64 + l4 * 16) ^ ((o_loc & 7) << 4)));
            }
            #pragma unroll
            for (int f = 0; f < 4; ++f)
                #pragma unroll
                for (int g = 0; g < 4; ++g)
                    acc[f][g] = __builtin_amdgcn_mfma_f32_16x16x32_bf16(a[f], bw[g], acc[f][g], 0, 0, 0);
        }
        __syncthreads();
    }

    #pragma unroll
    for (int g = 0; g < 4; ++g) {
        int og = ot * 128 + wwo * 64 + g * 16 + l15;
        float bias = b_dc[og];
        float* op = out + ((size_t)b * OO + og) * HW + posr + wp * 64 + l4 * 4;
        #pragma unroll
        for (int f = 0; f < 4; ++f) {
            f32x4 r = acc[f][g];
            float4 st;
            st.x = r[0] + bias; st.y = r[1] + bias;
            st.z = r[2] + bias; st.w = r[3] + bias;
            *(float4*)(op + f * 16) = st;
        }
    }
}

extern "C" void kernel_launch(void* const* d_in, const int* in_sizes, int n_in,
                              void* d_out, int out_size, void* d_ws, size_t ws_size,
                              hipStream_t stream)
{
    const float* x     = (const float*)d_in[0];
    const float* w_off = (const float*)d_in[1];
    const float* b_off = (const float*)d_in[2];
    const float* w_dc  = (const float*)d_in[3];
    const float* b_dc  = (const float*)d_in[4];
    float* out = (float*)d_out;

    if (ws_size >= WS_NEED) {
        char*  ws   = (char*)d_ws;
        char*  Vg   = ws;
        char*  Wb   = ws + WS_WB_OFF;
        uint4* meta = (uint4*)(ws + WS_META_OFF);
        offset_meta_kernel<<<BB * 144, 256, 0, stream>>>(x, w_off, b_off, meta);
        wconv_kernel<<<288, 256, 0, stream>>>(w_dc, Wb);
        gather_kernel3<<<288 * 9, 256, 0, stream>>>(x, meta, Vg);
        gemm_kernel<<<576, 256, 0, stream>>>(Vg, Wb, b_dc, out);
    } else {
        float* off = (float*)d_ws;
        offset_conv6_kernel<<<BB * 36 * 3, 256, 0, stream>>>(x, w_off, b_off, off);
        deform_mfma_kernel<<<(OO / 128) * (BB * HW / 128), 256, 0, stream>>>(x, off, w_dc, b_dc, out);
    }
}

// Round 7
// 341.936 us; speedup vs baseline: 1.8640x; 1.8387x over previous
//
#include <hip/hip_runtime.h>
#include <math.h>

#define BB   4
#define CC   256
#define HH   96
#define WW   96
#define OO   256
#define HW   9216        // HH*WW
#define KDIM 2304        // CC*9
#define OFFC 18
#define NKC  36          // K chunks of 64

// K ordering for the deform GEMM (split path): k' = tap*256 + c  (tap-major).
// V, Wb, and offset_meta's A/W staging all use k'; GEMM is ordering-agnostic.

typedef short bf16x8 __attribute__((ext_vector_type(8)));
typedef float f32x4  __attribute__((ext_vector_type(4)));
typedef unsigned int u32x4 __attribute__((ext_vector_type(4)));

// ---- ws layout (split path) ----
#define WS_V_SZ    (36864ull * 4608ull)               // V bf16 [p][k'], row 4608B, pre-swizzled
#define WS_WB_OFF  WS_V_SZ
#define WS_WB_SZ   (256ull * 4608ull)                 // W bf16 [o][k'], pre-swizzled
#define WS_META_OFF (WS_WB_OFF + WS_WB_SZ)
#define WS_META_SZ (4ull * 9ull * 9216ull * 16ull)    // uint4 per (b,tap,p)
#define WS_NEED    (WS_META_OFF + WS_META_SZ)         // ~176.4 MB

__device__ __forceinline__ unsigned short f2bfu(float f) {
    unsigned u = __float_as_uint(f);
    unsigned r = (u + 0x7fffu + ((u >> 16) & 1u)) >> 16;   // RNE
    return (unsigned short)r;
}
__device__ __forceinline__ unsigned pack2(float lo, float hi) {
    return (unsigned)f2bfu(lo) | ((unsigned)f2bfu(hi) << 16);
}
__device__ __forceinline__ void gload16(const void* g, void* l) {
    __builtin_amdgcn_global_load_lds((const __attribute__((address_space(1))) void*)g,
                                     (__attribute__((address_space(3))) void*)l, 16, 0, 0);
}

__device__ __forceinline__ uint4 make_meta(int pr, int t, float dy, float dx) {
    int oh = pr / WW, ow = pr - oh * WW;
    float py = (float)(oh - 1 + t / 3) + dy;
    float px = (float)(ow - 1 + (t % 3)) + dx;
    float y0f = floorf(py), x0f = floorf(px);
    int y0 = (int)y0f, x0 = (int)x0f;
    float ly = py - y0f, lx = px - x0f;
    float wy0 = (y0 >= 0 && y0 < HH) ? 1.f - ly : 0.f;
    float wy1 = (y0 + 1 >= 0 && y0 + 1 < HH) ? ly : 0.f;
    float u0 = (x0 >= 0 && x0 < WW) ? 1.f - lx : 0.f;
    float u1 = (x0 + 1 >= 0 && x0 + 1 < WW) ? lx : 0.f;
    int pb = min(max(x0, 0), WW - 2);
    float s0, s1;
    if (x0 < 0)           { s0 = u1; s1 = 0.f; }
    else if (x0 > WW - 2) { s0 = 0.f; s1 = u0; }
    else                  { s0 = u0; s1 = u1; }
    int cy0 = min(max(y0, 0), HH - 1);
    int cy1 = min(max(y0 + 1, 0), HH - 1);
    uint4 m;
    m.x = (unsigned)(cy0 * WW + pb);
    m.y = (unsigned)(cy1 * WW + pb);
    m.z = pack2(wy0 * s0, wy0 * s1);
    m.w = pack2(wy1 * s0, wy1 * s1);
    return m;
}

// ================= SPLIT PATH =================

// ---- Kernel A: offset conv via MFMA (64p x 32oc tile) + direct meta emission ----
// k' ordering: chunk kc -> tap = kc>>2, c-base = (kc&3)*64
__global__ __launch_bounds__(256)
void offset_meta_kernel(const float* __restrict__ x,
                        const float* __restrict__ w_off,
                        const float* __restrict__ b_off,
                        uint4* __restrict__ meta_ws)
{
    __shared__ __align__(16) char Asw[64 * 128];
    __shared__ __align__(16) char Wl[32 * 128];
    __shared__ float Dsh[64][21];

    const int tid = threadIdx.x;
    const int fin = ((blockIdx.x & 7) * 72) + (blockIdx.x >> 3);  // XCD-chunked (576 = 8*72)
    const int b   = fin / 144;
    const int pr0 = (fin % 144) * 64;
    const float* xb = x + (size_t)b * CC * HW;

    const int l15 = tid & 15;
    const int l4  = (tid >> 4) & 3;
    const int wav = tid >> 6;
    const int sp  = tid & 63;       // A staging: p row
    const int kq  = tid >> 6;       // A staging: c quarter (16 c)
    const int so  = tid >> 3;       // W staging: o row 0..31
    const int sq  = tid & 7;        // W staging: q group (8 c)

    const int prg = pr0 + sp;
    const int oh = prg / WW, ow = prg - (prg / WW) * WW;

    f32x4 acc[2];
    acc[0] = (f32x4){0.f, 0.f, 0.f, 0.f};
    acc[1] = (f32x4){0.f, 0.f, 0.f, 0.f};

    for (int kc = 0; kc < NKC; ++kc) {
        const int tap = kc >> 2;
        const int cb  = (kc & 3) * 64;
        // stage W (fp32 -> bf16, swizzled); rows 18..31 zero. w_off[so][c][tap], stride-9
        {
            uint4 pk;
            if (so < OFFC) {
                const float* wr = w_off + (size_t)so * KDIM + (cb + sq * 8) * 9 + tap;
                float wv[8];
                #pragma unroll
                for (int i = 0; i < 8; ++i) wv[i] = wr[i * 9];
                pk.x = pack2(wv[0], wv[1]); pk.y = pack2(wv[2], wv[3]);
                pk.z = pack2(wv[4], wv[5]); pk.w = pack2(wv[6], wv[7]);
            } else { pk.x = pk.y = pk.z = pk.w = 0u; }
            *(uint4*)(Wl + so * 128 + ((sq * 16) ^ ((so & 7) << 4))) = pk;
        }
        // stage A: static-tap gather, 16 c per thread (fixed tap -> bounds once)
        {
            int iy = oh + tap / 3 - 1;
            int ix = ow + tap % 3 - 1;
            bool ok = (iy >= 0) & (iy < HH) & (ix >= 0) & (ix < WW);
            const float* xp = xb + (size_t)(cb + kq * 16) * HW + iy * WW + ix;
            float v[16];
            #pragma unroll
            for (int e = 0; e < 16; ++e)
                v[e] = ok ? xp[(size_t)e * HW] : 0.f;
            char* arow = Asw + sp * 128;
            unsigned swz = (unsigned)((sp & 7) << 4);
            uint4 p0, p1;
            p0.x = pack2(v[0], v[1]);   p0.y = pack2(v[2], v[3]);
            p0.z = pack2(v[4], v[5]);   p0.w = pack2(v[6], v[7]);
            p1.x = pack2(v[8], v[9]);   p1.y = pack2(v[10], v[11]);
            p1.z = pack2(v[12], v[13]); p1.w = pack2(v[14], v[15]);
            *(uint4*)(arow + (((unsigned)(kq * 32 + 0)) ^ swz)) = p0;
            *(uint4*)(arow + (((unsigned)(kq * 32 + 16)) ^ swz)) = p1;
        }
        __syncthreads();
        // MFMA: wave handles p-frag wav*16, oc-frags 0..1
        {
            int p_loc = wav * 16 + l15;
            unsigned aswz = (unsigned)((p_loc & 7) << 4);
            #pragma unroll
            for (int ks = 0; ks < 2; ++ks) {
                bf16x8 a = *(const bf16x8*)(Asw + p_loc * 128 + ((ks * 64 + l4 * 16) ^ aswz));
                #pragma unroll
                for (int g = 0; g < 2; ++g) {
                    int o_loc = g * 16 + l15;
                    bf16x8 bw = *(const bf16x8*)(Wl + o_loc * 128 +
                                                 ((ks * 64 + l4 * 16) ^ ((o_loc & 7) << 4)));
                    acc[g] = __builtin_amdgcn_mfma_f32_16x16x32_bf16(a, bw, acc[g], 0, 0, 0);
                }
            }
        }
        __syncthreads();
    }

    // D -> LDS (rows p, cols oc<18), add bias
    #pragma unroll
    for (int g = 0; g < 2; ++g) {
        int o = g * 16 + l15;
        if (o < OFFC) {
            float bo = b_off[o];
            #pragma unroll
            for (int r = 0; r < 4; ++r)
                Dsh[wav * 16 + l4 * 4 + r][o] = acc[g][r] + bo;
        }
    }
    __syncthreads();
    // meta: 9 taps x 64 positions
    for (int s = tid; s < 9 * 64; s += 256) {
        int t = s >> 6, pl = s & 63;
        int pr = pr0 + pl;
        float dy = Dsh[pl][2 * t];
        float dx = Dsh[pl][2 * t + 1];
        meta_ws[((size_t)b * 9 + t) * HW + pr] = make_meta(pr, t, dy, dx);
    }
}

// ---- Kernel B: w_dc fp32 -> bf16 pre-swizzled, k' = tap*256 + c ----
__global__ __launch_bounds__(256)
void wconv_kernel(const float* __restrict__ w_dc, char* __restrict__ wb)
{
    int idx = blockIdx.x * 256 + (int)threadIdx.x;   // 73728 = 256 o * 288 (36 chunk * 8 q)
    int o   = idx / 288;
    int rem = idx - o * 288;
    int ch  = rem >> 3;          // chunk 0..35
    int q   = rem & 7;           // q group
    int tap = ch >> 2;
    int c0  = (ch & 3) * 64 + q * 8;
    const float* wr = w_dc + (size_t)o * KDIM + (size_t)c0 * 9 + tap;
    float wv[8];
    #pragma unroll
    for (int i = 0; i < 8; ++i) wv[i] = wr[i * 9];
    uint4 pk;
    pk.x = pack2(wv[0], wv[1]); pk.y = pack2(wv[2], wv[3]);
    pk.z = pack2(wv[4], wv[5]); pk.w = pack2(wv[6], wv[7]);
    *(uint4*)(wb + (size_t)o * 4608 + ch * 128 + ((q * 16) ^ ((o & 7) << 4))) = pk;
}

// ---- Kernel C: bilinear gather -> V[p][k'] bf16 (pre-swizzled rows) ----
// block = (pt, kc): 128 positions x 64 channels of ONE tap.
// Reads: lanes = 64 consecutive positions, same channel -> coalesced.
// Meta: one uint4 per thread, in registers (tap fixed per block).
// Writes: LDS transpose tile -> full-line coalesced 128B row chunks.
__global__ __launch_bounds__(256, 8)
void gather_kernel4(const float* __restrict__ x,
                    const uint4* __restrict__ meta_ws,
                    char* __restrict__ Vg)
{
    __shared__ uint4 Lmeta[128];
    __shared__ __align__(16) char Vl[128 * 128];   // [p][64 k' bf16], swizzled content

    int bid = blockIdx.x;                          // 10368 = 8 * 1296
    int fin = (bid & 7) * 1296 + (bid >> 3);       // XCD-chunked
    int ptg = fin / NKC;                           // p-tile 0..287
    int kc  = fin - ptg * NKC;                     // k' chunk 0..35
    int tap = kc >> 2;
    int b   = ptg / 72;
    int tid = threadIdx.x;

    if (tid < 128)
        Lmeta[tid] = meta_ws[((size_t)b * 9 + tap) * HW + (ptg % 72) * 128 + tid];
    __syncthreads();

    const int j = tid & 127, khalf = tid >> 7;
    uint4 m = Lmeta[j];
    const float wa0 = __uint_as_float(m.z << 16);
    const float wa1 = __uint_as_float(m.z & 0xffff0000u);
    const float wb0 = __uint_as_float(m.w << 16);
    const float wb1 = __uint_as_float(m.w & 0xffff0000u);

    const int c0 = (kc & 3) * 64 + khalf * 32;
    const float* xc = x + ((size_t)b * CC + c0) * HW;
    const float* pA = xc + m.x;
    const float* pB = xc + m.y;
    char* vrow = Vl + j * 128;
    const unsigned swz = (unsigned)((j & 7) << 4);

    #pragma unroll
    for (int g = 0; g < 4; ++g) {                  // 4 groups of 8 channels
        float v[8];
        #pragma unroll
        for (int e = 0; e < 8; ++e) {
            float A0 = pA[0], A1 = pA[1];
            float B0 = pB[0], B1 = pB[1];
            v[e] = fmaf(wa0, A0, fmaf(wa1, A1, fmaf(wb0, B0, wb1 * B1)));
            pA += HW; pB += HW;
        }
        u32x4 pk;
        pk.x = pack2(v[0], v[1]); pk.y = pack2(v[2], v[3]);
        pk.z = pack2(v[4], v[5]); pk.w = pack2(v[6], v[7]);
        *(u32x4*)(vrow + (((unsigned)(khalf * 64 + g * 16)) ^ swz)) = pk;
    }
    __syncthreads();

    // write-out: LDS (already-swizzled content) -> Vg rows, 128B per row chunk
    char* dst = Vg + (size_t)(ptg * 128) * 4608 + (size_t)kc * 128;
    #pragma unroll
    for (int i = 0; i < 4; ++i) {
        int idx = i * 256 + tid;
        int row = idx >> 3, colg = (idx & 7) * 16;
        *(uint4*)(dst + (size_t)row * 4608 + colg) =
            *(const uint4*)(Vl + row * 128 + colg);
    }
}

// ---- Kernel D: streaming GEMM, 2-phase double-buffered, global_load_lds ----
__global__ __launch_bounds__(256)
void gemm_kernel(const char* __restrict__ Vg, const char* __restrict__ Wb,
                 const float* __restrict__ b_dc, float* __restrict__ out)
{
    __shared__ __align__(16) char Ab[2][128 * 128];
    __shared__ __align__(16) char Bb[2][128 * 128];

    int bid = blockIdx.x;
    int swzb = (bid & 7) * 72 + (bid >> 3);   // both ot of a pt share an XCD
    int pt = swzb >> 1, ot = swzb & 1;
    int tid = threadIdx.x;
    int lane = tid & 63, wav = tid >> 6;
    const int l15 = tid & 15, l4 = (tid >> 4) & 3;
    const int wp = wav >> 1, wo = wav & 1;

    const char* Ag = Vg + (size_t)(pt * 128) * 4608;
    const char* Bg = Wb + (size_t)(ot * 128) * 4608;
    const int rsub = lane >> 3;
    const int csub = (lane & 7) * 16;

    f32x4 acc[4][4];
    #pragma unroll
    for (int f = 0; f < 4; ++f)
        #pragma unroll
        for (int g = 0; g < 4; ++g)
            acc[f][g] = (f32x4){0.f, 0.f, 0.f, 0.f};

#define STAGE(bufi, t) {                                                        \
        const char* ag = Ag + (size_t)(t) * 128;                                \
        const char* bg = Bg + (size_t)(t) * 128;                                \
        _Pragma("unroll")                                                       \
        for (int i = 0; i < 4; ++i) {                                           \
            int r0 = wav * 32 + i * 8;                                          \
            gload16(ag + (size_t)(r0 + rsub) * 4608 + csub, &Ab[bufi][r0 * 128]);\
            gload16(bg + (size_t)(r0 + rsub) * 4608 + csub, &Bb[bufi][r0 * 128]);\
        } }

    STAGE(0, 0);
    __syncthreads();

    int cur = 0;
    for (int t = 0; t < NKC; ++t) {
        if (t + 1 < NKC) STAGE(cur ^ 1, t + 1);
        #pragma unroll
        for (int ks = 0; ks < 2; ++ks) {
            bf16x8 a[4], bw[4];
            #pragma unroll
            for (int f = 0; f < 4; ++f) {
                int p_loc = wp * 64 + f * 16 + l15;
                a[f] = *(const bf16x8*)(Ab[cur] + p_loc * 128 +
                                        ((ks * 64 + l4 * 16) ^ ((p_loc & 7) << 4)));
            }
            #pragma unroll
            for (int g = 0; g < 4; ++g) {
                int o_loc = wo * 64 + g * 16 + l15;
                bw[g] = *(const bf16x8*)(Bb[cur] + o_loc * 128 +
                                         ((ks * 64 + l4 * 16) ^ ((o_loc & 7) << 4)));
            }
            #pragma unroll
            for (int f = 0; f < 4; ++f)
                #pragma unroll
                for (int g = 0; g < 4; ++g)
                    acc[f][g] = __builtin_amdgcn_mfma_f32_16x16x32_bf16(a[f], bw[g], acc[f][g], 0, 0, 0);
        }
        __syncthreads();
        cur ^= 1;
    }

    int b = pt / 72;
    int posr = (pt - b * 72) * 128;
    #pragma unroll
    for (int g = 0; g < 4; ++g) {
        int og = ot * 128 + wo * 64 + g * 16 + l15;
        float bias = b_dc[og];
        float* op = out + ((size_t)b * OO + og) * HW + posr + wp * 64 + l4 * 4;
        #pragma unroll
        for (int f = 0; f < 4; ++f) {
            f32x4 r = acc[f][g];
            float4 st;
            st.x = r[0] + bias; st.y = r[1] + bias;
            st.z = r[2] + bias; st.w = r[3] + bias;
            *(float4*)(op + f * 16) = st;
        }
    }
}

// ================= FALLBACK PATH (round-2, verified; self-consistent k ordering) =================

__global__ __launch_bounds__(256)
void offset_conv6_kernel(const float* __restrict__ x,
                         const float* __restrict__ w_off,
                         const float* __restrict__ b_off,
                         float* __restrict__ off)
{
    int bid   = blockIdx.x;
    int g     = bid % 3;
    int chunk = (bid / 3) % 36;
    int b     = bid / 108;
    int ocb   = g * 6;
    int pr    = chunk * 256 + (int)threadIdx.x;
    int oh    = pr / WW, ow = pr % WW;
    const float* xb = x + (size_t)b * CC * HW;

    float acc[6];
    #pragma unroll
    for (int i = 0; i < 6; ++i) acc[i] = b_off[ocb + i];

    bool interior = (oh >= 1) & (oh < HH - 1) & (ow >= 1) & (ow < WW - 1);
    if (interior) {
        const float* xp = xb + (oh - 1) * WW + (ow - 1);
        float xv[9];
        #pragma unroll
        for (int t = 0; t < 9; ++t) xv[t] = xp[(t / 3) * WW + (t % 3)];
        for (int c = 0; c < CC; ++c) {
            float xn[9];
            if (c + 1 < CC) {
                const float* xq = xp + (size_t)(c + 1) * HW;
                #pragma unroll
                for (int t = 0; t < 9; ++t) xn[t] = xq[(t / 3) * WW + (t % 3)];
            }
            #pragma unroll
            for (int i = 0; i < 6; ++i) {
                const float* wr = w_off + ((size_t)(ocb + i) * CC + c) * 9;
                #pragma unroll
                for (int t = 0; t < 9; ++t)
                    acc[i] = fmaf(xv[t], wr[t], acc[i]);
            }
            #pragma unroll
            for (int t = 0; t < 9; ++t) xv[t] = xn[t];
        }
    } else {
        for (int c = 0; c < CC; ++c) {
            const float* xc = xb + (size_t)c * HW;
            float xv[9];
            #pragma unroll
            for (int t = 0; t < 9; ++t) {
                int yy = oh + t / 3 - 1, xx = ow + t % 3 - 1;
                xv[t] = (yy >= 0 && yy < HH && xx >= 0 && xx < WW) ? xc[yy * WW + xx] : 0.f;
            }
            #pragma unroll
            for (int i = 0; i < 6; ++i) {
                const float* wr = w_off + ((size_t)(ocb + i) * CC + c) * 9;
                #pragma unroll
                for (int t = 0; t < 9; ++t)
                    acc[i] = fmaf(xv[t], wr[t], acc[i]);
            }
        }
    }
    #pragma unroll
    for (int i = 0; i < 6; ++i)
        off[((size_t)b * OFFC + ocb + i) * HW + pr] = acc[i];
}

__global__ __launch_bounds__(256)
void deform_mfma_kernel(const float* __restrict__ x,
                        const float* __restrict__ off,
                        const float* __restrict__ w_dc,
                        const float* __restrict__ b_dc,
                        float* __restrict__ out)
{
    __shared__ __align__(16) char VlB[128 * 128];
    __shared__ __align__(16) char WlB[128 * 128];
    __shared__ uint4 meta[9][128];

    const int tid  = threadIdx.x;
    const int ot   = blockIdx.x / 288;
    const int pt   = blockIdx.x % 288;
    const int pos0 = pt * 128;
    const int b    = pos0 / HW;
    const int posr = pos0 - b * HW;

    const float* offp = off + (size_t)b * OFFC * HW;
    for (int s = tid; s < 9 * 128; s += 256) {
        int tt = s >> 7, j = s & 127;
        int pr = posr + j;
        float dy = offp[(2 * tt) * HW + pr];
        float dx = offp[(2 * tt + 1) * HW + pr];
        meta[tt][j] = make_meta(pr, tt, dy, dx);
    }
    __syncthreads();

    const int l15 = tid & 15;
    const int l4  = (tid >> 4) & 3;
    const int wav = tid >> 6;
    const int wp  = wav >> 1, wwo = wav & 1;
    const int j     = tid & 127;
    const int khalf = tid >> 7;
    const int wo_o  = tid >> 4;
    const int wk    = (tid & 15) * 4;

    const float* wbase = w_dc + (size_t)(ot * 128) * KDIM;

    f32x4 acc[4][4];
    #pragma unroll
    for (int f = 0; f < 4; ++f)
        #pragma unroll
        for (int g = 0; g < 4; ++g)
            acc[f][g] = (f32x4){0.f, 0.f, 0.f, 0.f};

    for (int k0 = 0; k0 < KDIM; k0 += 64) {
        #pragma unroll
        for (int r = 0; r < 8; ++r) {
            int o = r * 16 + wo_o;
            const float4 wv = *(const float4*)(wbase + (size_t)o * KDIM + k0 + wk);
            uint2 u;
            u.x = pack2(wv.x, wv.y);
            u.y = pack2(wv.z, wv.w);
            *(uint2*)(WlB + o * 128 + ((wk * 2) ^ ((o & 7) << 4))) = u;
        }
        {
            unsigned kb = (unsigned)(k0 + khalf * 32);
            unsigned c  = kb / 9u;
            unsigned tt = kb - c * 9u;
            const float* xc = x + (size_t)((unsigned)b * CC + c) * HW;
            char* vrow = VlB + j * 128;
            const unsigned swz = (unsigned)((j & 7) << 4);
            #pragma unroll
            for (int g = 0; g < 4; ++g) {
                float v[8];
                #pragma unroll
                for (int e = 0; e < 8; ++e) {
                    uint4 m = meta[tt][j];
                    float A0 = xc[m.x], A1 = xc[m.x + 1];
                    float B0 = xc[m.y], B1 = xc[m.y + 1];
                    float a0 = __uint_as_float(m.z << 16);
                    float a1 = __uint_as_float(m.z & 0xffff0000u);
                    float b0 = __uint_as_float(m.w << 16);
                    float b1 = __uint_as_float(m.w & 0xffff0000u);
                    v[e] = fmaf(a0, A0, fmaf(a1, A1, fmaf(b0, B0, b1 * B1)));
                    ++tt;
                    if (tt == 9u) { tt = 0u; xc += HW; }
                }
                uint4 pk;
                pk.x = pack2(v[0], v[1]); pk.y = pack2(v[2], v[3]);
                pk.z = pack2(v[4], v[5]); pk.w = pack2(v[6], v[7]);
                *(uint4*)(vrow + (((unsigned)(khalf * 64 + g * 16)) ^ swz)) = pk;
            }
        }
        __syncthreads();

        #pragma unroll
        for (int ks = 0; ks < 2; ++ks) {
            bf16x8 a[4], bw[4];
            #pragma unroll
            for (int f = 0; f < 4; ++f) {
                int p_loc = wp * 64 + f * 16 + l15;
                a[f] = *(const bf16x8*)(VlB + p_loc * 128 +
                                        ((ks * 64 + l4 * 16) ^ ((p_loc & 7) << 4)));
            }
            #pragma unroll
            for (int g = 0; g < 4; ++g) {
                int o_loc = wwo * 64 + g * 16 + l15;
                bw[g] = *(const bf16x8*)(WlB + o_loc * 128 +
                                         ((ks * 64 + l4 * 16) ^ ((o_loc & 7) << 4)));
            }
            #pragma unroll
            for (int f = 0; f < 4; ++f)
                #pragma unroll
                for (int g = 0; g < 4; ++g)
                    acc[f][g] = __builtin_amdgcn_mfma_f32_16x16x32_bf16(a[f], bw[g], acc[f][g], 0, 0, 0);
        }
        __syncthreads();
    }

    #pragma unroll
    for (int g = 0; g < 4; ++g) {
        int og = ot * 128 + wwo * 64 + g * 16 + l15;
        float bias = b_dc[og];
        float* op = out + ((size_t)b * OO + og) * HW + posr + wp * 64 + l4 * 4;
        #pragma unroll
        for (int f = 0; f < 4; ++f) {
            f32x4 r = acc[f][g];
            float4 st;
            st.x = r[0] + bias; st.y = r[1] + bias;
            st.z = r[2] + bias; st.w = r[3] + bias;
            *(float4*)(op + f * 16) = st;
        }
    }
}

extern "C" void kernel_launch(void* const* d_in, const int* in_sizes, int n_in,
                              void* d_out, int out_size, void* d_ws, size_t ws_size,
                              hipStream_t stream)
{
    const float* x     = (const float*)d_in[0];
    const float* w_off = (const float*)d_in[1];
    const float* b_off = (const float*)d_in[2];
    const float* w_dc  = (const float*)d_in[3];
    const float* b_dc  = (const float*)d_in[4];
    float* out = (float*)d_out;

    if (ws_size >= WS_NEED) {
        char*  ws   = (char*)d_ws;
        char*  Vg   = ws;
        char*  Wb   = ws + WS_WB_OFF;
        uint4* meta = (uint4*)(ws + WS_META_OFF);
        offset_meta_kernel<<<BB * 144, 256, 0, stream>>>(x, w_off, b_off, meta);
        wconv_kernel<<<288, 256, 0, stream>>>(w_dc, Wb);
        gather_kernel4<<<288 * NKC, 256, 0, stream>>>(x, meta, Vg);
        gemm_kernel<<<576, 256, 0, stream>>>(Vg, Wb, b_dc, out);
    } else {
        float* off = (float*)d_ws;
        offset_conv6_kernel<<<BB * 36 * 3, 256, 0, stream>>>(x, w_off, b_off, off);
        deform_mfma_kernel<<<(OO / 128) * (BB * HW / 128), 256, 0, stream>>>(x, off, w_dc, b_dc, out);
    }
}